// Round 12
// baseline (267.975 us; speedup 1.0000x reference)
//
#include <hip/hip_runtime.h>

// GraphConv: B=16, S=50000, FIN=FOUT=16, T=64, E=8M
// R12: R11 post-mortem — pull (148us) runs at 2.25TB/s effective vs the
// 2.9TB/s this path sustains: the mask-pop gather dropped R7's 2-deep
// software pipeline (zero load->use slack). Restore it ACROSS the whole
// mask sequence (carry prefetched rec through all 8 octant loops + tail).
// Also fuse transpose into the place launch (independent stages, place
// blocks first) to hide its 13us. Sort/banding/place logic FROZEN.
#define BNUM 16
#define NCOL 800000   // S*FIN
#define NROW 800000   // S*FOUT
#define RPB  1024     // rows per bin
#define NBIN 782      // ceil(NROW/RPB)
#define HB   1024     // padded bin count (10-bit key)
#define PR   8192     // edges per place block
#define PT   512      // place/fused threads
#define CAPF 11264    // slab capacity per bin (mean 10240, +10 sigma)

#define WG_ADD(p, v) __hip_atomic_fetch_add((p), (v), __ATOMIC_RELAXED, __HIP_MEMORY_SCOPE_WORKGROUP)

// ---- bf16 <-> f32 helpers (bit-exact RNE) ----
__device__ __forceinline__ unsigned short f2bf(float f) {
    unsigned u = __float_as_uint(f);
    unsigned r = (u + 0x7fffu + ((u >> 16) & 1u)) >> 16;   // round-nearest-even
    return (unsigned short)r;
}
__device__ __forceinline__ float bf2f(unsigned short h) {
    return __uint_as_float(((unsigned)h) << 16);
}

// ballot-based equal-key mask + rank within group (wave-parallel, no atomics)
template <int BITS>
__device__ __forceinline__ void brank(unsigned key, bool v, int lane,
                                      int& rank, int& gsz) {
    unsigned long long vm = __ballot(v);
    unsigned long long eq = ~0ull;
#pragma unroll
    for (int b = 0; b < BITS; ++b) {
        unsigned long long bb = __ballot((key >> b) & 1u);
        eq &= ((key >> b) & 1u) ? bb : ~bb;
    }
    eq &= vm;
    rank = __popcll(eq & ((1ull << lane) - 1ull));
    gsz  = __popcll(eq);
}

// standalone transpose (fallback path only)
__global__ __launch_bounds__(256) void k_transpose_x(const float* __restrict__ x,
                                                     unsigned* __restrict__ xT) {
    int c = blockIdx.x * 256 + threadIdx.x;
    if (c >= NCOL) return;
    unsigned p[8];
#pragma unroll
    for (int b = 0; b < 8; ++b) {
        float lo = x[(size_t)(2 * b)     * NCOL + c];
        float hi = x[(size_t)(2 * b + 1) * NCOL + c];
        p[b] = (unsigned)f2bf(lo) | ((unsigned)f2bf(hi) << 16);
    }
    uint4* dst = reinterpret_cast<uint4*>(xT + (size_t)c * 8);
    dst[0] = make_uint4(p[0], p[1], p[2], p[3]);
    dst[1] = make_uint4(p[4], p[5], p[6], p[7]);
}

// init slab cursors: cursor[b] = b * CAPF
__global__ __launch_bounds__(1024) void k_init(unsigned* __restrict__ cursor) {
    int t = threadIdx.x;
    cursor[t] = (unsigned)t * CAPF;
}

// FUSED: blocks [0, pblocks) run R7-frozen place; blocks [pblocks, +1563)
// run the x->xT transpose (independent stages overlap on the machine).
__global__ __launch_bounds__(PT) void k_fused(const int* __restrict__ rows,
                                              const int* __restrict__ cols,
                                              const int* __restrict__ et,
                                              unsigned* __restrict__ cursor,
                                              unsigned* __restrict__ recA,
                                              unsigned short* __restrict__ recB,
                                              int E, int pblocks,
                                              const float* __restrict__ x,
                                              unsigned* __restrict__ xT) {
    __shared__ unsigned cnt[HB];      // hist, then reused as rank cursor
    __shared__ unsigned lofs[HB];     // local exclusive offsets
    __shared__ unsigned gbase[HB];    // reserved slab bases
    __shared__ unsigned srtA[PR];     // col|type, bin-sorted
    __shared__ unsigned srtR[PR];     // (bin<<10) | lrow
    __shared__ unsigned wsum[8];

    int t = threadIdx.x;

    if ((int)blockIdx.x >= pblocks) {
        // ---- transpose branch (512-thread variant of the proven kernel) ----
        int c = ((int)blockIdx.x - pblocks) * PT + t;
        if (c < NCOL) {
            unsigned p[8];
#pragma unroll
            for (int b = 0; b < 8; ++b) {
                float lo = x[(size_t)(2 * b)     * NCOL + c];
                float hi = x[(size_t)(2 * b + 1) * NCOL + c];
                p[b] = (unsigned)f2bf(lo) | ((unsigned)f2bf(hi) << 16);
            }
            uint4* dst = reinterpret_cast<uint4*>(xT + (size_t)c * 8);
            dst[0] = make_uint4(p[0], p[1], p[2], p[3]);
            dst[1] = make_uint4(p[4], p[5], p[6], p[7]);
        }
        return;
    }

    // ---- place branch (R7-frozen verbatim) ----
    int c0 = blockIdx.x * PR;
    int c1 = min(E, c0 + PR);
    int tot = c1 - c0;

    for (int i = t; i < HB; i += PT) cnt[i] = 0u;
    __syncthreads();

    unsigned er[16], ec[16];
#pragma unroll
    for (int k = 0; k < 16; ++k) {
        int e = c0 + k * PT + t;
        if (e < c1) {
            int r  = __builtin_nontemporal_load(rows + e);
            int c  = __builtin_nontemporal_load(cols + e);
            int ty = __builtin_nontemporal_load(et + e);
            er[k] = (unsigned)r;
            ec[k] = (unsigned)c | ((unsigned)ty << 20);
        } else {
            er[k] = 0xFFFFFFFFu;
            ec[k] = 0u;
        }
    }
#pragma unroll
    for (int k = 0; k < 16; ++k)
        if (er[k] != 0xFFFFFFFFu) WG_ADD(&cnt[er[k] >> 10], 1u);
    __syncthreads();

    {
        unsigned a0 = cnt[2 * t];
        unsigned a1 = cnt[2 * t + 1];
        unsigned ts = a0 + a1;
        unsigned incl = ts;
        for (int off = 1; off < 64; off <<= 1) {
            unsigned n = __shfl_up(incl, off, 64);
            if ((t & 63) >= off) incl += n;
        }
        if ((t & 63) == 63) wsum[t >> 6] = incl;
        __syncthreads();
        unsigned pre = 0;
        for (int k2 = 0; k2 < (t >> 6); ++k2) pre += wsum[k2];
        unsigned ex = pre + incl - ts;
        lofs[2 * t]     = ex;
        lofs[2 * t + 1] = ex + a0;
    }
    __syncthreads();

    for (int i = t; i < HB; i += PT) {
        unsigned c = cnt[i];
        gbase[i] = c ? atomicAdd(&cursor[i], c) : 0u;
    }
    __syncthreads();
    for (int i = t; i < HB; i += PT) cnt[i] = 0u;
    __syncthreads();

#pragma unroll
    for (int k = 0; k < 16; ++k) {
        if (er[k] == 0xFFFFFFFFu) continue;
        unsigned b  = er[k] >> 10;
        unsigned lr = er[k] & 1023u;
        unsigned rk = WG_ADD(&cnt[b], 1u);
        unsigned j  = lofs[b] + rk;
        srtA[j] = ec[k];
        srtR[j] = (b << 10) | lr;
    }
    __syncthreads();

    for (int j = t; j < tot; j += PT) {
        unsigned rr = srtR[j];
        unsigned b  = rr >> 10;
        unsigned dst = gbase[b] + ((unsigned)j - lofs[b]);
        if (dst < (b + 1u) * CAPF) {            // slab overflow guard (~1e-25)
            recA[dst] = srtA[j];
            recB[dst] = (unsigned short)(rr & 1023u);
        }
    }
}

__device__ __forceinline__ void fma8(float* a, float wt, uint4 v, int base) {
    a[base + 0] += wt * bf2f((unsigned short)(v.x & 0xffffu));
    a[base + 1] += wt * bf2f((unsigned short)(v.x >> 16));
    a[base + 2] += wt * bf2f((unsigned short)(v.y & 0xffffu));
    a[base + 3] += wt * bf2f((unsigned short)(v.y >> 16));
    a[base + 4] += wt * bf2f((unsigned short)(v.z & 0xffffu));
    a[base + 5] += wt * bf2f((unsigned short)(v.z >> 16));
    a[base + 6] += wt * bf2f((unsigned short)(v.w & 0xffffu));
    a[base + 7] += wt * bf2f((unsigned short)(v.w >> 16));
}

// R12 pull: R7-verbatim ballot counting sort; octant-banded bitmask gather
// (R11) with a 2-deep software pipeline carried ACROSS the whole mask
// sequence (issue next load -> compute previous rec).
__global__ __launch_bounds__(1024) void k_pull(const unsigned* __restrict__ cursor,
                                               const unsigned* __restrict__ recA,
                                               const unsigned short* __restrict__ recB,
                                               const float* __restrict__ wt_tab,
                                               const unsigned* __restrict__ xT,
                                               float* __restrict__ out) {
    __shared__ unsigned short h16[16][RPB];    // 32KB wave-private hist/cursor
    __shared__ unsigned srt[CAPF];             // 44KB sorted payload
    __shared__ unsigned short ptr_[RPB + 1];   // 2KB row offsets
    __shared__ unsigned wsum[16];

    int tid = threadIdx.x, lane = tid & 63, wv = tid >> 6;
    int bin = blockIdx.x;
    unsigned sbeg = (unsigned)bin * CAPF;
    int n  = min((int)(cursor[bin] - sbeg), CAPF);
    int nr = (n + 1023) >> 10;                 // rounds (<=11)

    unsigned* hw = (unsigned*)h16;
    for (int i = tid; i < 16 * RPB / 2; i += 1024) hw[i] = 0u;
    __syncthreads();

    // phase A: ballot histogram by lrow (10 bits) — cached loads
    for (int c = 0; c < nr; ++c) {
        int idx = c * 1024 + tid;
        bool v = idx < n;
        unsigned key = 0u;
        if (v) key = recB[sbeg + idx] & (RPB - 1u);
        int rank, gsz;
        brank<10>(key, v, lane, rank, gsz);
        if (v && rank == 0)
            h16[wv][key] = (unsigned short)(h16[wv][key] + (unsigned)gsz);
    }
    __syncthreads();

    // scan 1024 row-bins (1/thread): wave prefix into h16, block scan -> ptr_
    {
        unsigned t0 = 0;
#pragma unroll
        for (int ww = 0; ww < 16; ++ww) {
            unsigned a = h16[ww][tid]; h16[ww][tid] = (unsigned short)t0; t0 += a;
        }
        unsigned incl = t0;
        for (int off = 1; off < 64; off <<= 1) {
            unsigned m = __shfl_up(incl, off, 64);
            if ((tid & 63) >= off) incl += m;
        }
        if ((tid & 63) == 63) wsum[tid >> 6] = incl;
        __syncthreads();
        unsigned pre = 0;
        for (int k = 0; k < (tid >> 6); ++k) pre += wsum[k];
        unsigned ex = pre + incl - t0;
        ptr_[tid] = (unsigned short)ex;
        if (tid == 1023) ptr_[RPB] = (unsigned short)n;
#pragma unroll
        for (int ww = 0; ww < 16; ++ww)
            h16[ww][tid] = (unsigned short)(h16[ww][tid] + ex);
    }
    __syncthreads();

    // phase B: reload (L2-hot), place payload into LDS sorted order
    for (int c = 0; c < nr; ++c) {
        int idx = c * 1024 + tid;
        bool v = idx < n;
        unsigned key = 0u, pay = 0u;
        if (v) {
            key = recB[sbeg + idx] & (RPB - 1u);
            pay = recA[sbeg + idx];
        }
        int rank, gsz;
        brank<10>(key, v, lane, rank, gsz);
        unsigned cur = h16[wv][key];
        if (v && rank == 0)
            h16[wv][key] = (unsigned short)(cur + (unsigned)gsz);
        if (v) srt[cur + (unsigned)rank] = pay;
    }
    __syncthreads();

    // gather: 1 thread per row; octant bitmasks (one build pass) + 2-deep
    // pipeline carried across all 8 phases and the tail.
    int r = tid;
    float a[16];
#pragma unroll
    for (int k = 0; k < 16; ++k) a[k] = 0.f;
    {
        int p0 = (int)ptr_[r];
        int p1 = (int)ptr_[r + 1];
        int len  = p1 - p0;
        int lcap = min(len, 32);

        unsigned m0 = 0, m1 = 0, m2 = 0, m3 = 0, m4 = 0, m5 = 0, m6 = 0, m7 = 0;
        for (int i = 0; i < lcap; ++i) {
            unsigned oct = (srt[p0 + i] >> 17) & 7u;
            unsigned bit = 1u << i;
            m0 |= (oct == 0u) ? bit : 0u;
            m1 |= (oct == 1u) ? bit : 0u;
            m2 |= (oct == 2u) ? bit : 0u;
            m3 |= (oct == 3u) ? bit : 0u;
            m4 |= (oct == 4u) ? bit : 0u;
            m5 |= (oct == 5u) ? bit : 0u;
            m6 |= (oct == 6u) ? bit : 0u;
            m7 |= (oct == 7u) ? bit : 0u;
        }

        unsigned pu = 0u;                       // pipelined previous rec
        uint4 plo = make_uint4(0, 0, 0, 0), phi = plo;
        bool have = false;

#define STEP_MASK(MQ)                                                         \
        {                                                                     \
            unsigned mask = (MQ);                                             \
            while (mask) {                                                    \
                int i = __ffs(mask) - 1;                                      \
                mask &= mask - 1u;                                            \
                unsigned nu = srt[p0 + i];                                    \
                const uint4* qp = reinterpret_cast<const uint4*>(             \
                    xT + (size_t)(nu & 0xFFFFFu) * 8);                        \
                uint4 nlo = qp[0], nhi = qp[1];                               \
                if (have) {                                                   \
                    float wt = wt_tab[pu >> 20];                              \
                    fma8(a, wt, plo, 0);                                      \
                    fma8(a, wt, phi, 8);                                      \
                }                                                             \
                pu = nu; plo = nlo; phi = nhi; have = true;                   \
            }                                                                 \
        }
        STEP_MASK(m0) STEP_MASK(m1) STEP_MASK(m2) STEP_MASK(m3)
        STEP_MASK(m4) STEP_MASK(m5) STEP_MASK(m6) STEP_MASK(m7)
#undef STEP_MASK

        // tail (len > 32, P ~ 8e-4 per run): same pipelined chain
        for (int p = p0 + 32; p < p1; ++p) {
            unsigned nu = srt[p];
            const uint4* qp = reinterpret_cast<const uint4*>(
                xT + (size_t)(nu & 0xFFFFFu) * 8);
            uint4 nlo = qp[0], nhi = qp[1];
            if (have) {
                float wt = wt_tab[pu >> 20];
                fma8(a, wt, plo, 0);
                fma8(a, wt, phi, 8);
            }
            pu = nu; plo = nlo; phi = nhi; have = true;
        }
        if (have) {                             // drain
            float wt = wt_tab[pu >> 20];
            fma8(a, wt, plo, 0);
            fma8(a, wt, phi, 8);
        }
    }
    int gr = bin * RPB + r;
    if (gr < NROW) {
#pragma unroll
        for (int k = 0; k < 16; ++k)
            __builtin_nontemporal_store(a[k], out + (size_t)k * NROW + gr);
    }
}

// ---------------- fallback path (atomic scatter, needs only 51.2MB) ----

__global__ __launch_bounds__(256) void k_scatter(const int* __restrict__ rows,
                                                 const int* __restrict__ cols,
                                                 const int* __restrict__ et,
                                                 const float* __restrict__ w,
                                                 const unsigned* __restrict__ xT,
                                                 unsigned short* __restrict__ outT,
                                                 int E) {
    long long tid = (long long)blockIdx.x * 256 + threadIdx.x;
    long long e = tid >> 3;
    if (e >= E) return;
    int j = (int)(tid & 7);
    int r = __builtin_nontemporal_load(rows + e);
    int c = __builtin_nontemporal_load(cols + e);
    int t = __builtin_nontemporal_load(et + e);
    float wt = w[t];
    unsigned px = xT[(size_t)c * 8 + j];
    float x0 = bf2f((unsigned short)(px & 0xffffu));
    float x1 = bf2f((unsigned short)(px >> 16));
    unsigned short b0 = f2bf(wt * x0);
    unsigned short b1 = f2bf(wt * x1);
    unsigned data = (unsigned)b0 | ((unsigned)b1 << 16);
    unsigned short* dst = outT + ((size_t)r * 16 + 2 * j);
    asm volatile("global_atomic_pk_add_bf16 %0, %1, off"
                 :: "v"(dst), "v"(data) : "memory");
}

__global__ __launch_bounds__(256) void k_transpose_out(const unsigned* __restrict__ outT,
                                                       float* __restrict__ out) {
    int r = blockIdx.x * 256 + threadIdx.x;
    if (r >= NROW) return;
    const uint4* src = reinterpret_cast<const uint4*>(outT + (size_t)r * 8);
    uint4 v0 = src[0], v1 = src[1];
    unsigned p[8] = {v0.x, v0.y, v0.z, v0.w, v1.x, v1.y, v1.z, v1.w};
#pragma unroll
    for (int b = 0; b < 8; ++b) {
        out[(size_t)(2 * b)     * NROW + r] = bf2f((unsigned short)(p[b] & 0xffffu));
        out[(size_t)(2 * b + 1) * NROW + r] = bf2f((unsigned short)(p[b] >> 16));
    }
}

extern "C" void kernel_launch(void* const* d_in, const int* in_sizes, int n_in,
                              void* d_out, int out_size, void* d_ws, size_t ws_size,
                              hipStream_t stream) {
    const float* x    = (const float*)d_in[0];
    const float* w    = (const float*)d_in[1];
    const int*   rows = (const int*)d_in[2];
    const int*   cols = (const int*)d_in[3];
    const int*   et   = (const int*)d_in[4];
    const int    E    = in_sizes[2];

    float* out = (float*)d_out;

    // ws layout: xT 25.6MB | recA u32[NBIN*CAPF] | recB u16[NBIN*CAPF] | cursor[1024]
    size_t xT_b    = (size_t)NCOL * 8 * 4;            // 25,600,000
    size_t slabN   = (size_t)NBIN * CAPF;             // 8,808,448 recs
    size_t rA_off  = xT_b;
    size_t rB_off  = rA_off + slabN * 4;
    size_t aux_off = (rB_off + slabN * 2 + 255) & ~(size_t)255;
    size_t needed  = aux_off + 1024 * 4;              // ~78.7MB

    unsigned* xT = (unsigned*)d_ws;

    if (ws_size >= needed) {
        unsigned*       recA   = (unsigned*)((char*)d_ws + rA_off);
        unsigned short* recB   = (unsigned short*)((char*)d_ws + rB_off);
        unsigned*       cursor = (unsigned*)((char*)d_ws + aux_off);

        k_init<<<1, 1024, 0, stream>>>(cursor);

        int pblocks = (E + PR - 1) / PR;                  // 977
        int tblocks = (NCOL + PT - 1) / PT;               // 1563
        k_fused<<<pblocks + tblocks, PT, 0, stream>>>(rows, cols, et, cursor,
                                                      recA, recB, E, pblocks,
                                                      x, xT);
        k_pull<<<NBIN, 1024, 0, stream>>>(cursor, recA, recB, w, xT, out);
    } else {
        // fallback: pk_add_bf16 atomic scatter (51.2MB ws)
        unsigned short* outT = (unsigned short*)d_ws;
        unsigned*       xT2  = (unsigned*)((char*)d_ws + (size_t)NROW * BNUM * 2);

        hipMemsetAsync(outT, 0, (size_t)NROW * BNUM * 2, stream);
        k_transpose_x<<<(NCOL + 255) / 256, 256, 0, stream>>>(x, xT2);

        long long total = (long long)E * 8;
        int blocks = (int)((total + 255) / 256);
        k_scatter<<<blocks, 256, 0, stream>>>(rows, cols, et, w, xT2, outT, E);
        k_transpose_out<<<(NROW + 255) / 256, 256, 0, stream>>>((const unsigned*)outT, out);
    }
}

// Round 13
// 225.237 us; speedup vs baseline: 1.1897x; 1.1897x over previous
//
#include <hip/hip_runtime.h>

// GraphConv: B=16, S=50000, FIN=FOUT=16, T=64, E=8M
// R13: R12 post-mortem — the cross-phase carried pipeline raised VGPR
// 28->44, achieved occupancy 60->35%, pull 148->193us: this kernel hides
// latency via TLP (occupancy), not ILP; trading registers for slack is
// net-negative. REVERT pull to R11-verbatim (148us, reproduced). KEEP the
// R12 fusion (place+transpose in one launch, ~75us vs 81us separate).
#define BNUM 16
#define NCOL 800000   // S*FIN
#define NROW 800000   // S*FOUT
#define RPB  1024     // rows per bin
#define NBIN 782      // ceil(NROW/RPB)
#define HB   1024     // padded bin count (10-bit key)
#define PR   8192     // edges per place block
#define PT   512      // place/fused threads
#define CAPF 11264    // slab capacity per bin (mean 10240, +10 sigma)

#define WG_ADD(p, v) __hip_atomic_fetch_add((p), (v), __ATOMIC_RELAXED, __HIP_MEMORY_SCOPE_WORKGROUP)

// ---- bf16 <-> f32 helpers (bit-exact RNE) ----
__device__ __forceinline__ unsigned short f2bf(float f) {
    unsigned u = __float_as_uint(f);
    unsigned r = (u + 0x7fffu + ((u >> 16) & 1u)) >> 16;   // round-nearest-even
    return (unsigned short)r;
}
__device__ __forceinline__ float bf2f(unsigned short h) {
    return __uint_as_float(((unsigned)h) << 16);
}

// ballot-based equal-key mask + rank within group (wave-parallel, no atomics)
template <int BITS>
__device__ __forceinline__ void brank(unsigned key, bool v, int lane,
                                      int& rank, int& gsz) {
    unsigned long long vm = __ballot(v);
    unsigned long long eq = ~0ull;
#pragma unroll
    for (int b = 0; b < BITS; ++b) {
        unsigned long long bb = __ballot((key >> b) & 1u);
        eq &= ((key >> b) & 1u) ? bb : ~bb;
    }
    eq &= vm;
    rank = __popcll(eq & ((1ull << lane) - 1ull));
    gsz  = __popcll(eq);
}

// standalone transpose (fallback path only)
__global__ __launch_bounds__(256) void k_transpose_x(const float* __restrict__ x,
                                                     unsigned* __restrict__ xT) {
    int c = blockIdx.x * 256 + threadIdx.x;
    if (c >= NCOL) return;
    unsigned p[8];
#pragma unroll
    for (int b = 0; b < 8; ++b) {
        float lo = x[(size_t)(2 * b)     * NCOL + c];
        float hi = x[(size_t)(2 * b + 1) * NCOL + c];
        p[b] = (unsigned)f2bf(lo) | ((unsigned)f2bf(hi) << 16);
    }
    uint4* dst = reinterpret_cast<uint4*>(xT + (size_t)c * 8);
    dst[0] = make_uint4(p[0], p[1], p[2], p[3]);
    dst[1] = make_uint4(p[4], p[5], p[6], p[7]);
}

// init slab cursors: cursor[b] = b * CAPF
__global__ __launch_bounds__(1024) void k_init(unsigned* __restrict__ cursor) {
    int t = threadIdx.x;
    cursor[t] = (unsigned)t * CAPF;
}

// FUSED (R12-measured): blocks [0, pblocks) run R7-frozen place; blocks
// [pblocks, +1563) run the x->xT transpose (independent stages overlap).
__global__ __launch_bounds__(PT) void k_fused(const int* __restrict__ rows,
                                              const int* __restrict__ cols,
                                              const int* __restrict__ et,
                                              unsigned* __restrict__ cursor,
                                              unsigned* __restrict__ recA,
                                              unsigned short* __restrict__ recB,
                                              int E, int pblocks,
                                              const float* __restrict__ x,
                                              unsigned* __restrict__ xT) {
    __shared__ unsigned cnt[HB];      // hist, then reused as rank cursor
    __shared__ unsigned lofs[HB];     // local exclusive offsets
    __shared__ unsigned gbase[HB];    // reserved slab bases
    __shared__ unsigned srtA[PR];     // col|type, bin-sorted
    __shared__ unsigned srtR[PR];     // (bin<<10) | lrow
    __shared__ unsigned wsum[8];

    int t = threadIdx.x;

    if ((int)blockIdx.x >= pblocks) {
        // ---- transpose branch (512-thread variant of the proven kernel) ----
        int c = ((int)blockIdx.x - pblocks) * PT + t;
        if (c < NCOL) {
            unsigned p[8];
#pragma unroll
            for (int b = 0; b < 8; ++b) {
                float lo = x[(size_t)(2 * b)     * NCOL + c];
                float hi = x[(size_t)(2 * b + 1) * NCOL + c];
                p[b] = (unsigned)f2bf(lo) | ((unsigned)f2bf(hi) << 16);
            }
            uint4* dst = reinterpret_cast<uint4*>(xT + (size_t)c * 8);
            dst[0] = make_uint4(p[0], p[1], p[2], p[3]);
            dst[1] = make_uint4(p[4], p[5], p[6], p[7]);
        }
        return;
    }

    // ---- place branch (R7-frozen verbatim) ----
    int c0 = blockIdx.x * PR;
    int c1 = min(E, c0 + PR);
    int tot = c1 - c0;

    for (int i = t; i < HB; i += PT) cnt[i] = 0u;
    __syncthreads();

    unsigned er[16], ec[16];
#pragma unroll
    for (int k = 0; k < 16; ++k) {
        int e = c0 + k * PT + t;
        if (e < c1) {
            int r  = __builtin_nontemporal_load(rows + e);
            int c  = __builtin_nontemporal_load(cols + e);
            int ty = __builtin_nontemporal_load(et + e);
            er[k] = (unsigned)r;
            ec[k] = (unsigned)c | ((unsigned)ty << 20);
        } else {
            er[k] = 0xFFFFFFFFu;
            ec[k] = 0u;
        }
    }
#pragma unroll
    for (int k = 0; k < 16; ++k)
        if (er[k] != 0xFFFFFFFFu) WG_ADD(&cnt[er[k] >> 10], 1u);
    __syncthreads();

    {
        unsigned a0 = cnt[2 * t];
        unsigned a1 = cnt[2 * t + 1];
        unsigned ts = a0 + a1;
        unsigned incl = ts;
        for (int off = 1; off < 64; off <<= 1) {
            unsigned n = __shfl_up(incl, off, 64);
            if ((t & 63) >= off) incl += n;
        }
        if ((t & 63) == 63) wsum[t >> 6] = incl;
        __syncthreads();
        unsigned pre = 0;
        for (int k2 = 0; k2 < (t >> 6); ++k2) pre += wsum[k2];
        unsigned ex = pre + incl - ts;
        lofs[2 * t]     = ex;
        lofs[2 * t + 1] = ex + a0;
    }
    __syncthreads();

    for (int i = t; i < HB; i += PT) {
        unsigned c = cnt[i];
        gbase[i] = c ? atomicAdd(&cursor[i], c) : 0u;
    }
    __syncthreads();
    for (int i = t; i < HB; i += PT) cnt[i] = 0u;
    __syncthreads();

#pragma unroll
    for (int k = 0; k < 16; ++k) {
        if (er[k] == 0xFFFFFFFFu) continue;
        unsigned b  = er[k] >> 10;
        unsigned lr = er[k] & 1023u;
        unsigned rk = WG_ADD(&cnt[b], 1u);
        unsigned j  = lofs[b] + rk;
        srtA[j] = ec[k];
        srtR[j] = (b << 10) | lr;
    }
    __syncthreads();

    for (int j = t; j < tot; j += PT) {
        unsigned rr = srtR[j];
        unsigned b  = rr >> 10;
        unsigned dst = gbase[b] + ((unsigned)j - lofs[b]);
        if (dst < (b + 1u) * CAPF) {            // slab overflow guard (~1e-25)
            recA[dst] = srtA[j];
            recB[dst] = (unsigned short)(rr & 1023u);
        }
    }
}

__device__ __forceinline__ void fma8(float* a, float wt, uint4 v, int base) {
    a[base + 0] += wt * bf2f((unsigned short)(v.x & 0xffffu));
    a[base + 1] += wt * bf2f((unsigned short)(v.x >> 16));
    a[base + 2] += wt * bf2f((unsigned short)(v.y & 0xffffu));
    a[base + 3] += wt * bf2f((unsigned short)(v.y >> 16));
    a[base + 4] += wt * bf2f((unsigned short)(v.z & 0xffffu));
    a[base + 5] += wt * bf2f((unsigned short)(v.z >> 16));
    a[base + 6] += wt * bf2f((unsigned short)(v.w & 0xffffu));
    a[base + 7] += wt * bf2f((unsigned short)(v.w >> 16));
}

// R13 pull: R11-VERBATIM (148us reproduced): ballot counting sort + octant
// bitmask banded gather (simple pop loops, 28 VGPR, TLP-hidden latency).
__global__ __launch_bounds__(1024) void k_pull(const unsigned* __restrict__ cursor,
                                               const unsigned* __restrict__ recA,
                                               const unsigned short* __restrict__ recB,
                                               const float* __restrict__ wt_tab,
                                               const unsigned* __restrict__ xT,
                                               float* __restrict__ out) {
    __shared__ unsigned short h16[16][RPB];    // 32KB wave-private hist/cursor
    __shared__ unsigned srt[CAPF];             // 44KB sorted payload
    __shared__ unsigned short ptr_[RPB + 1];   // 2KB row offsets
    __shared__ unsigned wsum[16];

    int tid = threadIdx.x, lane = tid & 63, wv = tid >> 6;
    int bin = blockIdx.x;
    unsigned sbeg = (unsigned)bin * CAPF;
    int n  = min((int)(cursor[bin] - sbeg), CAPF);
    int nr = (n + 1023) >> 10;                 // rounds (<=11)

    unsigned* hw = (unsigned*)h16;
    for (int i = tid; i < 16 * RPB / 2; i += 1024) hw[i] = 0u;
    __syncthreads();

    // phase A: ballot histogram by lrow (10 bits) — cached loads
    for (int c = 0; c < nr; ++c) {
        int idx = c * 1024 + tid;
        bool v = idx < n;
        unsigned key = 0u;
        if (v) key = recB[sbeg + idx] & (RPB - 1u);
        int rank, gsz;
        brank<10>(key, v, lane, rank, gsz);
        if (v && rank == 0)
            h16[wv][key] = (unsigned short)(h16[wv][key] + (unsigned)gsz);
    }
    __syncthreads();

    // scan 1024 row-bins (1/thread): wave prefix into h16, block scan -> ptr_
    {
        unsigned t0 = 0;
#pragma unroll
        for (int ww = 0; ww < 16; ++ww) {
            unsigned a = h16[ww][tid]; h16[ww][tid] = (unsigned short)t0; t0 += a;
        }
        unsigned incl = t0;
        for (int off = 1; off < 64; off <<= 1) {
            unsigned m = __shfl_up(incl, off, 64);
            if ((tid & 63) >= off) incl += m;
        }
        if ((tid & 63) == 63) wsum[tid >> 6] = incl;
        __syncthreads();
        unsigned pre = 0;
        for (int k = 0; k < (tid >> 6); ++k) pre += wsum[k];
        unsigned ex = pre + incl - t0;
        ptr_[tid] = (unsigned short)ex;
        if (tid == 1023) ptr_[RPB] = (unsigned short)n;
#pragma unroll
        for (int ww = 0; ww < 16; ++ww)
            h16[ww][tid] = (unsigned short)(h16[ww][tid] + ex);
    }
    __syncthreads();

    // phase B: reload (L2-hot), place payload into LDS sorted order
    for (int c = 0; c < nr; ++c) {
        int idx = c * 1024 + tid;
        bool v = idx < n;
        unsigned key = 0u, pay = 0u;
        if (v) {
            key = recB[sbeg + idx] & (RPB - 1u);
            pay = recA[sbeg + idx];
        }
        int rank, gsz;
        brank<10>(key, v, lane, rank, gsz);
        unsigned cur = h16[wv][key];
        if (v && rank == 0)
            h16[wv][key] = (unsigned short)(cur + (unsigned)gsz);
        if (v) srt[cur + (unsigned)rank] = pay;
    }
    __syncthreads();

    // gather: 1 thread per row; octant-banded via per-thread bitmasks.
    int r = tid;
    float a[16];
#pragma unroll
    for (int k = 0; k < 16; ++k) a[k] = 0.f;
    {
        int p0 = (int)ptr_[r];
        int p1 = (int)ptr_[r + 1];
        int len  = p1 - p0;
        int lcap = min(len, 32);

        // one pass: build 8 octant masks (named regs, unrolled compare-or)
        unsigned m0 = 0, m1 = 0, m2 = 0, m3 = 0, m4 = 0, m5 = 0, m6 = 0, m7 = 0;
        for (int i = 0; i < lcap; ++i) {
            unsigned oct = (srt[p0 + i] >> 17) & 7u;
            unsigned bit = 1u << i;
            m0 |= (oct == 0u) ? bit : 0u;
            m1 |= (oct == 1u) ? bit : 0u;
            m2 |= (oct == 2u) ? bit : 0u;
            m3 |= (oct == 3u) ? bit : 0u;
            m4 |= (oct == 4u) ? bit : 0u;
            m5 |= (oct == 5u) ? bit : 0u;
            m6 |= (oct == 6u) ? bit : 0u;
            m7 |= (oct == 7u) ? bit : 0u;
        }

#define GATHER_MASK(MQ)                                                       \
        {                                                                     \
            unsigned mask = (MQ);                                             \
            while (mask) {                                                    \
                int i = __ffs(mask) - 1;                                      \
                mask &= mask - 1u;                                            \
                unsigned u = srt[p0 + i];                                     \
                const uint4* qp = reinterpret_cast<const uint4*>(             \
                    xT + (size_t)(u & 0xFFFFFu) * 8);                         \
                uint4 lo = qp[0], hi = qp[1];                                 \
                float wt = wt_tab[u >> 20];                                   \
                fma8(a, wt, lo, 0);                                           \
                fma8(a, wt, hi, 8);                                           \
            }                                                                 \
        }
        GATHER_MASK(m0) GATHER_MASK(m1) GATHER_MASK(m2) GATHER_MASK(m3)
        GATHER_MASK(m4) GATHER_MASK(m5) GATHER_MASK(m6) GATHER_MASK(m7)
#undef GATHER_MASK

        // tail (len > 32, P ~ 8e-4 per run): unphased
        for (int p = p0 + 32; p < p1; ++p) {
            unsigned u = srt[p];
            const uint4* qp = reinterpret_cast<const uint4*>(
                xT + (size_t)(u & 0xFFFFFu) * 8);
            uint4 lo = qp[0], hi = qp[1];
            float wt = wt_tab[u >> 20];
            fma8(a, wt, lo, 0);
            fma8(a, wt, hi, 8);
        }
    }
    int gr = bin * RPB + r;
    if (gr < NROW) {
#pragma unroll
        for (int k = 0; k < 16; ++k)
            __builtin_nontemporal_store(a[k], out + (size_t)k * NROW + gr);
    }
}

// ---------------- fallback path (atomic scatter, needs only 51.2MB) ----

__global__ __launch_bounds__(256) void k_scatter(const int* __restrict__ rows,
                                                 const int* __restrict__ cols,
                                                 const int* __restrict__ et,
                                                 const float* __restrict__ w,
                                                 const unsigned* __restrict__ xT,
                                                 unsigned short* __restrict__ outT,
                                                 int E) {
    long long tid = (long long)blockIdx.x * 256 + threadIdx.x;
    long long e = tid >> 3;
    if (e >= E) return;
    int j = (int)(tid & 7);
    int r = __builtin_nontemporal_load(rows + e);
    int c = __builtin_nontemporal_load(cols + e);
    int t = __builtin_nontemporal_load(et + e);
    float wt = w[t];
    unsigned px = xT[(size_t)c * 8 + j];
    float x0 = bf2f((unsigned short)(px & 0xffffu));
    float x1 = bf2f((unsigned short)(px >> 16));
    unsigned short b0 = f2bf(wt * x0);
    unsigned short b1 = f2bf(wt * x1);
    unsigned data = (unsigned)b0 | ((unsigned)b1 << 16);
    unsigned short* dst = outT + ((size_t)r * 16 + 2 * j);
    asm volatile("global_atomic_pk_add_bf16 %0, %1, off"
                 :: "v"(dst), "v"(data) : "memory");
}

__global__ __launch_bounds__(256) void k_transpose_out(const unsigned* __restrict__ outT,
                                                       float* __restrict__ out) {
    int r = blockIdx.x * 256 + threadIdx.x;
    if (r >= NROW) return;
    const uint4* src = reinterpret_cast<const uint4*>(outT + (size_t)r * 8);
    uint4 v0 = src[0], v1 = src[1];
    unsigned p[8] = {v0.x, v0.y, v0.z, v0.w, v1.x, v1.y, v1.z, v1.w};
#pragma unroll
    for (int b = 0; b < 8; ++b) {
        out[(size_t)(2 * b)     * NROW + r] = bf2f((unsigned short)(p[b] & 0xffffu));
        out[(size_t)(2 * b + 1) * NROW + r] = bf2f((unsigned short)(p[b] >> 16));
    }
}

extern "C" void kernel_launch(void* const* d_in, const int* in_sizes, int n_in,
                              void* d_out, int out_size, void* d_ws, size_t ws_size,
                              hipStream_t stream) {
    const float* x    = (const float*)d_in[0];
    const float* w    = (const float*)d_in[1];
    const int*   rows = (const int*)d_in[2];
    const int*   cols = (const int*)d_in[3];
    const int*   et   = (const int*)d_in[4];
    const int    E    = in_sizes[2];

    float* out = (float*)d_out;

    // ws layout: xT 25.6MB | recA u32[NBIN*CAPF] | recB u16[NBIN*CAPF] | cursor[1024]
    size_t xT_b    = (size_t)NCOL * 8 * 4;            // 25,600,000
    size_t slabN   = (size_t)NBIN * CAPF;             // 8,808,448 recs
    size_t rA_off  = xT_b;
    size_t rB_off  = rA_off + slabN * 4;
    size_t aux_off = (rB_off + slabN * 2 + 255) & ~(size_t)255;
    size_t needed  = aux_off + 1024 * 4;              // ~78.7MB

    unsigned* xT = (unsigned*)d_ws;

    if (ws_size >= needed) {
        unsigned*       recA   = (unsigned*)((char*)d_ws + rA_off);
        unsigned short* recB   = (unsigned short*)((char*)d_ws + rB_off);
        unsigned*       cursor = (unsigned*)((char*)d_ws + aux_off);

        k_init<<<1, 1024, 0, stream>>>(cursor);

        int pblocks = (E + PR - 1) / PR;                  // 977
        int tblocks = (NCOL + PT - 1) / PT;               // 1563
        k_fused<<<pblocks + tblocks, PT, 0, stream>>>(rows, cols, et, cursor,
                                                      recA, recB, E, pblocks,
                                                      x, xT);
        k_pull<<<NBIN, 1024, 0, stream>>>(cursor, recA, recB, w, xT, out);
    } else {
        // fallback: pk_add_bf16 atomic scatter (51.2MB ws)
        unsigned short* outT = (unsigned short*)d_ws;
        unsigned*       xT2  = (unsigned*)((char*)d_ws + (size_t)NROW * BNUM * 2);

        hipMemsetAsync(outT, 0, (size_t)NROW * BNUM * 2, stream);
        k_transpose_x<<<(NCOL + 255) / 256, 256, 0, stream>>>(x, xT2);

        long long total = (long long)E * 8;
        int blocks = (int)((total + 255) / 256);
        k_scatter<<<blocks, 256, 0, stream>>>(rows, cols, et, w, xT2, outT, E);
        k_transpose_out<<<(NROW + 255) / 256, 256, 0, stream>>>((const unsigned*)outT, out);
    }
}